// Round 3
// baseline (310.956 us; speedup 1.0000x reference)
//
#include <hip/hip_runtime.h>
#include <hip/hip_bf16.h>

// Problem constants (from reference):
#define BSZ    64
#define DLEN   65536
#define NNODES 1024
#define NFEATS 256
#define EDIM   256
#define NROWS  (BSZ * NNODES)   // 65536 (b,node) rows

#define WPAD   268              // LDS win row stride in words: 16B-aligned, 2-way-max bank aliasing
#define HROWS  32               // rows (nodes) per gemm block
#define NBLK   (NROWS / HROWS)  // 2048 gemm blocks

// d_out doubles as the scatter window: u32 pack per (b,node,feat) slot.
// pack = ((d+1)<<15) | (bf16(val)>>1). Unsigned max over a slot is decided by
// d -> last-write-wins (matches reference .set() duplicate semantics),
// order-independent. Zero slot <=> never filled (d+1 >= 1).

typedef __bf16 bf16x8 __attribute__((ext_vector_type(8)));
typedef float  f32x4  __attribute__((ext_vector_type(4)));

// ---- bf16 helpers ----
__device__ __forceinline__ unsigned short f2bf(float x) {
  union { float f; unsigned u; } c; c.f = x;
  unsigned r = c.u + 0x7FFFu + ((c.u >> 16) & 1u);
  return (unsigned short)(r >> 16);
}

// ---- K0: zero the output window (+mask region) and convert W to bf16 ----
// 4112 blocks x 256 threads x 4 uint4 = 4,210,688 uint4 = 67.37 MB
// (= out_emb 64*1024*256 f32 + out_mask 65536 f32, exactly).
__global__ __launch_bounds__(256) void zero_wconv_kernel(
    const float* __restrict__ W, unsigned short* __restrict__ Wb,
    uint4* __restrict__ owin) {
  const int t = threadIdx.x;
  const int base = blockIdx.x * 1024 + t;
#pragma unroll
  for (int k = 0; k < 4; ++k)
    owin[base + k * 256] = make_uint4(0u, 0u, 0u, 0u);
  if (blockIdx.x < 64) {   // 64 blocks cover the 65536-word W matrix
    int i = (blockIdx.x * 256 + t) * 4;
    float4 w = *(const float4*)(W + i);
    ushort4 o;
    o.x = f2bf(w.x); o.y = f2bf(w.y); o.z = f2bf(w.z); o.w = f2bf(w.w);
    *(ushort4*)(Wb + i) = o;
  }
}

// ---- K1: direct global scatter. No LDS, no barriers, no capacity limits. ----
// Stream 16B-coalesced, 4 fire-and-forget global_atomic_umax per thread
// (result unused -> no-return). Dedup + priority handled by the pack format.
__global__ __launch_bounds__(512, 8) void scatter_kernel(
    const float* __restrict__ x, const int* __restrict__ nid,
    const int* __restrict__ fid, unsigned* __restrict__ win) {
  const int t = threadIdx.x;
  const int i = (blockIdx.x * 512 + t) * 4;     // element index, 16B-coalesced

  float4 xv = *(const float4*)(x + i);
  int4   nv = *(const int4*)(nid + i);
  int4   fv = *(const int4*)(fid + i);
  const unsigned bb = (((unsigned)i >> 16) << 18);   // batch*1024*256
  int   nd[4] = {nv.x, nv.y, nv.z, nv.w};
  int   ft[4] = {fv.x, fv.y, fv.z, fv.w};
  float vl[4] = {xv.x, xv.y, xv.z, xv.w};
#pragma unroll
  for (int j = 0; j < 4; ++j) {
    unsigned d = (unsigned)(i + j) & 0xFFFFu;
    unsigned pack = ((d + 1u) << 15) | ((unsigned)f2bf(vl[j]) >> 1);
    unsigned addr = bb | ((unsigned)nd[j] << 8) | (unsigned)ft[j];
    atomicMax(win + addr, pack);
  }
}

// ---- K2: dense window -> LDS, popcount counts, bf16 MFMA GEMM, in-place epilogue ----
// Block g owns rows g*32..+32 (32 nodes x 256 feats). It stages ITS OWN window
// slice (32 KB, coalesced, no atomics), so reading d_out and overwriting it
// in the epilogue is race-free (stage completes at the barrier before writes).
// 512 threads: wave w covers cols w*32..+32. MFMA 16x16x32 bf16 mapping:
// A[m=lane&15][k=q*8+j], B[k=q*8+j][n=lane&15], D[m=q*4+reg][n=lane&15].
__global__ __launch_bounds__(512, 8) void gemm_kernel(
    const unsigned short* __restrict__ Wb, const float* __restrict__ bias,
    const float* __restrict__ gemb,
    float* __restrict__ out_emb, float* __restrict__ out_mask) {
  __shared__ __align__(16) unsigned win[HROWS * WPAD];  // 34.3 KB padded window
  __shared__ float scl[HROWS];

  const int t = threadIdx.x;
  const int g = blockIdx.x;                // bucket id
  const int row0 = g * HROWS;              // global output row base
  const int nb = (g & 31) * HROWS;         // node base within gemb

  // stage: 2048 uint4 (32 rows x 64 uint4), 4 per thread, coalesced reads,
  // LDS rows padded to WPAD words.
  {
    const uint4* src = (const uint4*)out_emb + (size_t)row0 * 64;
    uint4 v[4];
#pragma unroll
    for (int k = 0; k < 4; ++k) v[k] = src[t + k * 512];
#pragma unroll
    for (int k = 0; k < 4; ++k) {
      int idx = t + k * 512;
      *(uint4*)&win[(idx >> 6) * WPAD + (idx & 63) * 4] = v[k];
    }
  }
  __syncthreads();

  // counts via popcount scan: 16 threads per row, each scans 4 uint4,
  // strided 16 so a wave's lanes land ~2-way-max on banks (row stride 67 uint4).
  {
    const int lr  = t >> 4;           // 0..31
    const int seg = t & 15;
    const uint4* rowp = (const uint4*)&win[lr * WPAD];
    int c = 0;
#pragma unroll
    for (int j = 0; j < 4; ++j) {
      uint4 w = rowp[seg + 16 * j];
      c += (w.x != 0u) + (w.y != 0u) + (w.z != 0u) + (w.w != 0u);
    }
    c += __shfl_down(c, 8, 16);
    c += __shfl_down(c, 4, 16);
    c += __shfl_down(c, 2, 16);
    c += __shfl_down(c, 1, 16);
    if (seg == 0) {
      scl[lr] = c ? 1.0f / (float)c : 0.0f;   // cnt==0 -> nan_to_num => 0
      out_mask[row0 + lr] = c ? 0.0f : 1.0f;
    }
  }

  // GEMM: wave w computes rows 0..31 x cols w*32..+32.
  const int wv   = t >> 6;            // 0..7
  const int lane = t & 63;
  const int cl   = lane & 15;
  const int q    = lane >> 4;
  const int col0 = wv * 32;

  f32x4 acc[2][2];
#pragma unroll
  for (int mt = 0; mt < 2; ++mt)
#pragma unroll
    for (int nt = 0; nt < 2; ++nt) acc[mt][nt] = (f32x4)(0.0f);

#pragma unroll
  for (int ks = 0; ks < 8; ++ks) {
    bf16x8 bfr[2];
#pragma unroll
    for (int nt = 0; nt < 2; ++nt) {
      const uint4* wp = (const uint4*)(Wb + (size_t)(col0 + nt * 16 + cl) * NFEATS + ks * 32 + q * 8);
      bfr[nt] = __builtin_bit_cast(bf16x8, *wp);
    }
#pragma unroll
    for (int mt = 0; mt < 2; ++mt) {
      const uint4* ap = (const uint4*)&win[(mt * 16 + cl) * WPAD + ks * 32 + q * 8];
      uint4 lo = ap[0], hi = ap[1];
      uint4 pk;  // (p&0x7FFF)<<1 is the bf16 bit pattern; pack pairs little-endian
      pk.x = ((lo.x & 0x7FFFu) << 1) | ((lo.y & 0x7FFFu) << 17);
      pk.y = ((lo.z & 0x7FFFu) << 1) | ((lo.w & 0x7FFFu) << 17);
      pk.z = ((hi.x & 0x7FFFu) << 1) | ((hi.y & 0x7FFFu) << 17);
      pk.w = ((hi.z & 0x7FFFu) << 1) | ((hi.w & 0x7FFFu) << 17);
      bf16x8 afr = __builtin_bit_cast(bf16x8, pk);
#pragma unroll
      for (int nt = 0; nt < 2; ++nt)
        acc[mt][nt] = __builtin_amdgcn_mfma_f32_16x16x32_bf16(afr, bfr[nt], acc[mt][nt], 0, 0, 0);
    }
  }
  __syncthreads();   // scl visibility before epilogue

  // epilogue: out = acc/cnt + bias + gemb  (overwrites the staged window rows)
#pragma unroll
  for (int nt = 0; nt < 2; ++nt) {
    int col = col0 + nt * 16 + cl;
    float bv = bias[col];
#pragma unroll
    for (int mt = 0; mt < 2; ++mt) {
#pragma unroll
      for (int r2 = 0; r2 < 4; ++r2) {
        int row = mt * 16 + q * 4 + r2;
        float o = acc[mt][nt][r2] * scl[row] + bv + gemb[(size_t)(nb + row) * EDIM + col];
        out_emb[(size_t)(row0 + row) * EDIM + col] = o;
      }
    }
  }
}

extern "C" void kernel_launch(void* const* d_in, const int* in_sizes, int n_in,
                              void* d_out, int out_size, void* d_ws, size_t ws_size,
                              hipStream_t stream) {
  const float* x    = (const float*)d_in[0];   // flat_inputs (64,65536) f32
  const int*   nid  = (const int*)d_in[1];     // node_ids    (64,65536) i32
  const int*   fid  = (const int*)d_in[2];     // feat_ids    (64,65536) i32
  const float* W    = (const float*)d_in[3];   // (256,256) f32 (embed, feat)
  const float* bias = (const float*)d_in[4];   // (256,)
  const float* gemb = (const float*)d_in[5];   // (1024,256) f32

  float* out_emb  = (float*)d_out;                   // f32 (64,1024,256)
  float* out_mask = out_emb + (size_t)NROWS * EDIM;  // f32 (64,1024,1)

  // ws layout: [Wb 128KB]  (record buffer + counters eliminated)
  unsigned short* Wb = (unsigned short*)d_ws;

  zero_wconv_kernel<<<4112, 256, 0, stream>>>(W, Wb, (uint4*)out_emb);
  scatter_kernel<<<(BSZ * DLEN) / 2048, 512, 0, stream>>>(x, nid, fid, (unsigned*)out_emb);
  gemm_kernel<<<NBLK, 512, 0, stream>>>(Wb, bias, gemb, out_emb, out_mask);
}

// Round 4
// 148.318 us; speedup vs baseline: 2.0965x; 2.0965x over previous
//
#include <hip/hip_runtime.h>
#include <hip/hip_bf16.h>

// Problem constants (from reference):
#define BSZ    64
#define DLEN   65536
#define NNODES 1024
#define NFEATS 256
#define EDIM   256
#define NROWS  (BSZ * NNODES)   // 65536 (b,node) rows

// Bucketing geometry: 16 node-ranges of 64 nodes per batch (round-0 optimum).
#define NRANGE  16
#define NBUCKET (BSZ * NRANGE)  // 1024
#define LCAP    320             // per-block per-range LDS cap (mean 256, sd 15.5; overflow -> global path)
#define GCAP    4600            // per-bucket global capacity (mean 4096, sd 62 -> +8.1 sigma)
#define WPAD    268             // win row stride in words: 16B-aligned, 2-way-max LDS bank aliasing

typedef __bf16 bf16x8 __attribute__((ext_vector_type(8)));
typedef float  f32x4  __attribute__((ext_vector_type(4)));

// ---- bf16 helpers ----
__device__ __forceinline__ unsigned short f2bf(float x) {
  union { float f; unsigned u; } c; c.f = x;
  unsigned r = c.u + 0x7FFFu + ((c.u >> 16) & 1u);
  return (unsigned short)(r >> 16);
}

// ---- K1: bucketize obs by (batch, node-range), LDS-staged, coalesced flush ----
// Also folds the W->bf16 conversion into blocks 0..31 (kills the wconv launch).
// record = { pack = ((d+1)<<15)|(bf16(val)>>1),  y = (row<<16)|(row*WPAD+feat) }
// pack's unsigned max over same slot is decided by d -> last-write-wins,
// order-independent, so append order never matters.
__global__ __launch_bounds__(512, 8) void bucket_kernel(
    const float* __restrict__ x, const int* __restrict__ nid,
    const int* __restrict__ fid, unsigned* __restrict__ gcnt,
    uint2* __restrict__ gbuf,
    const float* __restrict__ W, unsigned short* __restrict__ Wb) {
  __shared__ uint2 lbuf[NRANGE][LCAP];   // 40 KB
  __shared__ unsigned lcnt[NRANGE];
  __shared__ unsigned lbase[NRANGE];

  const int t = threadIdx.x;
  if (t < NRANGE) lcnt[t] = 0;

  // W conversion: 32 blocks x 512 threads x 4 words = 65536 (independent work,
  // issued before the barrier so it overlaps the bucketing phase).
  if (blockIdx.x < 32) {
    int wi = (blockIdx.x * 512 + t) * 4;
    float4 w = *(const float4*)(W + wi);
    ushort4 o;
    o.x = f2bf(w.x); o.y = f2bf(w.y); o.z = f2bf(w.z); o.w = f2bf(w.w);
    *(ushort4*)(Wb + wi) = o;
  }
  __syncthreads();

  const int b = blockIdx.x >> 4;          // 16 blocks per batch
  const int base = blockIdx.x * 4096;

#pragma unroll
  for (int k = 0; k < 2; ++k) {
    int i = base + (k * 512 + t) * 4;     // 16B-coalesced
    float4 xv = *(const float4*)(x + i);
    int4   nv = *(const int4*)(nid + i);
    int4   fv = *(const int4*)(fid + i);
    int   nd[4] = {nv.x, nv.y, nv.z, nv.w};
    int   ft[4] = {fv.x, fv.y, fv.z, fv.w};
    float vl[4] = {xv.x, xv.y, xv.z, xv.w};
#pragma unroll
    for (int j = 0; j < 4; ++j) {
      int d = (i + j) & 0xFFFF;
      unsigned pack = (((unsigned)(d + 1)) << 15) | ((unsigned)f2bf(vl[j]) >> 1);
      int r = nd[j] >> 6;
      unsigned row = (unsigned)(nd[j] & 63);
      uint2 rec;
      rec.x = pack;
      rec.y = (row << 16) | (row * WPAD + (unsigned)ft[j]);
      unsigned li = atomicAdd(&lcnt[r], 1u);
      if (li < LCAP) {
        lbuf[r][li] = rec;
      } else {                             // rare overflow: direct global append
        unsigned gi = atomicAdd(&gcnt[b * NRANGE + r], 1u);
        if (gi < GCAP) gbuf[(size_t)(b * NRANGE + r) * GCAP + gi] = rec;
      }
    }
  }
  __syncthreads();

  if (t < NRANGE) {
    unsigned n = lcnt[t]; if (n > LCAP) n = LCAP;
    lcnt[t] = n;
    lbase[t] = atomicAdd(&gcnt[b * NRANGE + t], n);
  }
  __syncthreads();

  for (int r = 0; r < NRANGE; ++r) {
    unsigned n  = lcnt[r];
    unsigned bs = lbase[r];
    uint2* dst = gbuf + (size_t)(b * NRANGE + r) * GCAP;
    for (unsigned j = t; j < n; j += 512) {
      unsigned gi = bs + j;
      if (gi < GCAP) dst[gi] = lbuf[r][j];   // coalesced
    }
  }
}

// ---- K2: LDS window (dedup, no-return ds_max) + bf16 MFMA GEMM + epilogue ----
// Block g = b*16+r: rows row0=g*64..+64 (64 nodes x 256 feats), out 64x256.
// Record-chunk loads are all pre-issued (5 predicated uint4 loads in flight)
// before the atomic burst. Distinct counts recovered post-hoc by popcount
// scan (slot nonzero <=> filled, pack >= 0x8000) -- no returning atomics.
// 512 threads: wave w covers cols w*32..+32. MFMA 16x16x32 bf16 mapping:
// A[m=lane&15][k=q*8+j], B[k=q*8+j][n=lane&15], D[m=q*4+reg][n=lane&15].
__global__ __launch_bounds__(512, 4) void fused_kernel(
    const unsigned* __restrict__ gcnt, const uint2* __restrict__ gbuf,
    const unsigned short* __restrict__ Wb, const float* __restrict__ bias,
    const float* __restrict__ gemb,
    float* __restrict__ out_emb, float* __restrict__ out_mask) {
  __shared__ __align__(16) unsigned win[64 * WPAD];  // 68.6 KB packed window
  __shared__ float scl[64];

  const int t = threadIdx.x;
  const int g = blockIdx.x;           // = b*16 + r
  const int row0 = g * 64;
  const int nb = (g & 15) * 64;       // node base within gemb

  // zero window
  uint4* wz = (uint4*)win;
  for (int j = t; j < (64 * WPAD) / 4; j += 512) wz[j] = make_uint4(0u, 0u, 0u, 0u);
  __syncthreads();

  // phase 1: dedup scatter into LDS. Pre-issue all chunk loads (np <= 2300
  // -> at most 5 chunks of 512), then fire the no-return atomics.
  int cn = (int)gcnt[g]; if (cn > GCAP) cn = GCAP;
  const uint2* bk = gbuf + (size_t)g * GCAP;
  const uint4* bk4 = (const uint4*)bk;
  int np = cn >> 1;
  {
    uint4 r0, r1, r2, r3, r4;
    bool v0 = t < np, v1 = t + 512 < np, v2 = t + 1024 < np,
         v3 = t + 1536 < np, v4 = t + 2048 < np;
    if (v0) r0 = bk4[t];
    if (v1) r1 = bk4[t + 512];
    if (v2) r2 = bk4[t + 1024];
    if (v3) r3 = bk4[t + 1536];
    if (v4) r4 = bk4[t + 2048];
    if (v0) { atomicMax(&win[r0.y & 0xFFFFu], r0.x); atomicMax(&win[r0.w & 0xFFFFu], r0.z); }
    if (v1) { atomicMax(&win[r1.y & 0xFFFFu], r1.x); atomicMax(&win[r1.w & 0xFFFFu], r1.z); }
    if (v2) { atomicMax(&win[r2.y & 0xFFFFu], r2.x); atomicMax(&win[r2.w & 0xFFFFu], r2.z); }
    if (v3) { atomicMax(&win[r3.y & 0xFFFFu], r3.x); atomicMax(&win[r3.w & 0xFFFFu], r3.z); }
    if (v4) { atomicMax(&win[r4.y & 0xFFFFu], r4.x); atomicMax(&win[r4.w & 0xFFFFu], r4.z); }
    if ((cn & 1) && t == 0) {
      uint2 rec = bk[cn - 1];
      atomicMax(&win[rec.y & 0xFFFFu], rec.x);
    }
  }
  __syncthreads();

  // phase 1.5: distinct counts via popcount scan. 8 threads per row; each
  // thread scans 8 of the 64 data-uint4s of its row, strided by 8 (row
  // stride 67 uint4 keeps a wave's lanes ~2-way-max on banks).
  {
    const int lr  = t >> 3;           // 0..63
    const int seg = t & 7;
    const uint4* rowp = (const uint4*)&win[lr * WPAD];
    int c = 0;
#pragma unroll
    for (int j = 0; j < 8; ++j) {
      uint4 w = rowp[seg + 8 * j];
      c += (w.x != 0u) + (w.y != 0u) + (w.z != 0u) + (w.w != 0u);
    }
    c += __shfl_down(c, 4, 8);
    c += __shfl_down(c, 2, 8);
    c += __shfl_down(c, 1, 8);
    if (seg == 0) {
      scl[lr] = c ? 1.0f / (float)c : 0.0f;   // cnt==0 -> nan_to_num => 0
      out_mask[row0 + lr] = c ? 0.0f : 1.0f;
    }
  }

  // phase 2: MFMA GEMM. Wave w computes rows 0..63 x cols w*32..+32.
  // (win read-only from here; scl consumed after the post-GEMM barrier.)
  const int wv   = t >> 6;            // 0..7
  const int lane = t & 63;
  const int cl   = lane & 15;
  const int q    = lane >> 4;
  const int col0 = wv * 32;

  f32x4 acc[4][2];
#pragma unroll
  for (int mt = 0; mt < 4; ++mt)
#pragma unroll
    for (int nt = 0; nt < 2; ++nt) acc[mt][nt] = (f32x4)(0.0f);

#pragma unroll
  for (int ks = 0; ks < 8; ++ks) {
    bf16x8 bfr[2];
#pragma unroll
    for (int nt = 0; nt < 2; ++nt) {
      const uint4* wp = (const uint4*)(Wb + (size_t)(col0 + nt * 16 + cl) * NFEATS + ks * 32 + q * 8);
      bfr[nt] = __builtin_bit_cast(bf16x8, *wp);
    }
#pragma unroll
    for (int mt = 0; mt < 4; ++mt) {
      const uint4* ap = (const uint4*)&win[(mt * 16 + cl) * WPAD + ks * 32 + q * 8];
      uint4 lo = ap[0], hi = ap[1];
      uint4 pk;  // (p&0x7FFF)<<1 is the bf16 bit pattern; pack pairs little-endian
      pk.x = ((lo.x & 0x7FFFu) << 1) | ((lo.y & 0x7FFFu) << 17);
      pk.y = ((lo.z & 0x7FFFu) << 1) | ((lo.w & 0x7FFFu) << 17);
      pk.z = ((hi.x & 0x7FFFu) << 1) | ((hi.y & 0x7FFFu) << 17);
      pk.w = ((hi.z & 0x7FFFu) << 1) | ((hi.w & 0x7FFFu) << 17);
      bf16x8 afr = __builtin_bit_cast(bf16x8, pk);
#pragma unroll
      for (int nt = 0; nt < 2; ++nt)
        acc[mt][nt] = __builtin_amdgcn_mfma_f32_16x16x32_bf16(afr, bfr[nt], acc[mt][nt], 0, 0, 0);
    }
  }
  __syncthreads();   // scl visibility before epilogue

  // epilogue: out = acc/cnt + bias + gemb
#pragma unroll
  for (int nt = 0; nt < 2; ++nt) {
    int col = col0 + nt * 16 + cl;
    float bv = bias[col];
#pragma unroll
    for (int mt = 0; mt < 4; ++mt) {
#pragma unroll
      for (int r2 = 0; r2 < 4; ++r2) {
        int row = mt * 16 + q * 4 + r2;
        float o = acc[mt][nt][r2] * scl[row] + bv + gemb[(size_t)(nb + row) * EDIM + col];
        out_emb[(size_t)(row0 + row) * EDIM + col] = o;
      }
    }
  }
}

extern "C" void kernel_launch(void* const* d_in, const int* in_sizes, int n_in,
                              void* d_out, int out_size, void* d_ws, size_t ws_size,
                              hipStream_t stream) {
  const float* x    = (const float*)d_in[0];   // flat_inputs (64,65536) f32
  const int*   nid  = (const int*)d_in[1];     // node_ids    (64,65536) i32
  const int*   fid  = (const int*)d_in[2];     // feat_ids    (64,65536) i32
  const float* W    = (const float*)d_in[3];   // (256,256) f32 (embed, feat)
  const float* bias = (const float*)d_in[4];   // (256,)
  const float* gemb = (const float*)d_in[5];   // (1024,256) f32

  float* out_emb  = (float*)d_out;                   // f32 (64,1024,256)
  float* out_mask = out_emb + (size_t)NROWS * EDIM;  // f32 (64,1024,1)

  // ws layout: [gcnt 4KB (pad to 8KB)] [gbuf 1024*4600*8B = 37.7MB] [Wb 128KB]
  unsigned* gcnt = (unsigned*)d_ws;
  uint2* gbuf = (uint2*)((char*)d_ws + 8192);
  unsigned short* Wb = (unsigned short*)((char*)d_ws + 8192 + (size_t)NBUCKET * GCAP * sizeof(uint2));

  hipMemsetAsync(gcnt, 0, NBUCKET * sizeof(unsigned), stream);
  bucket_kernel<<<(BSZ * DLEN) / 4096, 512, 0, stream>>>(x, nid, fid, gcnt, gbuf, W, Wb);
  fused_kernel<<<NBUCKET, 512, 0, stream>>>(gcnt, gbuf, Wb, bias, gemb, out_emb, out_mask);
}